// Round 2
// baseline (45.067 us; speedup 1.0000x reference)
//
#include <hip/hip_runtime.h>

// mem_update_MSF: LIF-style membrane update with multi-synaptic fire.
// x: [T=8, B=32, C=128, H=32, W=32] f32.  out same shape, f32 spike counts.
// Recurrence per neuron i:
//   mask = spike>0; mem = mem*0.25*(1-mask) + x[t]; spike = sum_d (mem >= 0.5+d)
// Memory-bound streaming: 268 MB logical traffic, no reuse across neurons.
// R1: hoist all 8 loads ahead of the carry chain (8 loads in flight/thread)
//     to cover HBM latency with ILP, not just TLP.

constexpr int T = 8;

__device__ __forceinline__ float msf_count(float m) {
    // Explicit threshold compares — exact match to the reference's Heaviside sum.
    float s = (m >= 0.5f) ? 1.0f : 0.0f;
    s += (m >= 1.5f) ? 1.0f : 0.0f;
    s += (m >= 2.5f) ? 1.0f : 0.0f;
    s += (m >= 3.5f) ? 1.0f : 0.0f;
    return s;
}

__global__ __launch_bounds__(256) void mem_update_msf_kernel(
        const float4* __restrict__ x, float4* __restrict__ out, int NV) {
    int i = blockIdx.x * blockDim.x + threadIdx.x;
    if (i >= NV) return;

    // Issue all T loads up front — independent addresses, 8 dwordx4 in flight.
    float4 xt[T];
#pragma unroll
    for (int t = 0; t < T; ++t) {
        xt[t] = x[(size_t)t * NV + i];
    }

    float m0 = 0.f, m1 = 0.f, m2 = 0.f, m3 = 0.f;
    float s0 = 0.f, s1 = 0.f, s2 = 0.f, s3 = 0.f;

#pragma unroll
    for (int t = 0; t < T; ++t) {
        // keep = (1 - mask) is exactly 0.0 or 1.0; mem*0.25 is an exact
        // exponent shift -> single rounding at the add, matches numpy bitwise.
        m0 = m0 * 0.25f * ((s0 > 0.f) ? 0.f : 1.f) + xt[t].x;
        m1 = m1 * 0.25f * ((s1 > 0.f) ? 0.f : 1.f) + xt[t].y;
        m2 = m2 * 0.25f * ((s2 > 0.f) ? 0.f : 1.f) + xt[t].z;
        m3 = m3 * 0.25f * ((s3 > 0.f) ? 0.f : 1.f) + xt[t].w;

        s0 = msf_count(m0);
        s1 = msf_count(m1);
        s2 = msf_count(m2);
        s3 = msf_count(m3);

        float4 o;
        o.x = s0; o.y = s1; o.z = s2; o.w = s3;
        out[(size_t)t * NV + i] = o;
    }
}

extern "C" void kernel_launch(void* const* d_in, const int* in_sizes, int n_in,
                              void* d_out, int out_size, void* d_ws, size_t ws_size,
                              hipStream_t stream) {
    const float* x = (const float*)d_in[0];
    float* out = (float*)d_out;

    const int total = out_size;          // T * B * C * H * W = 33,554,432
    const int N = total / T;             // neurons per timestep = 4,194,304
    const int NV = N / 4;                // float4 groups = 1,048,576

    const int block = 256;
    const int grid = (NV + block - 1) / block;  // 4096

    mem_update_msf_kernel<<<grid, block, 0, stream>>>(
        (const float4*)x, (float4*)out, NV);
}

// Round 3
// 44.808 us; speedup vs baseline: 1.0058x; 1.0058x over previous
//
#include <hip/hip_runtime.h>

// mem_update_MSF: LIF-style membrane update with multi-synaptic fire.
// x: [T=8, B=32, C=128, H=32, W=32] f32.  out same shape, f32 spike counts.
// Recurrence per neuron i:
//   mask = spike>0; mem = mem*0.25*(1-mask) + x[t]; spike = sum_d (mem >= 0.5+d)
// Memory-bound streaming.
// R2: non-temporal stores for `out` so the 134MB output stream doesn't evict
//     x from the 256MB Infinity Cache; across graph replays x becomes fully
//     L3-resident (R1 profile: FETCH_SIZE was already only 65MB = half-resident).

constexpr int T = 8;

typedef float f32x4 __attribute__((ext_vector_type(4)));

__device__ __forceinline__ float msf_count(float m) {
    // Explicit threshold compares — exact match to the reference's Heaviside sum.
    float s = (m >= 0.5f) ? 1.0f : 0.0f;
    s += (m >= 1.5f) ? 1.0f : 0.0f;
    s += (m >= 2.5f) ? 1.0f : 0.0f;
    s += (m >= 3.5f) ? 1.0f : 0.0f;
    return s;
}

__global__ __launch_bounds__(256) void mem_update_msf_kernel(
        const f32x4* __restrict__ x, f32x4* __restrict__ out, int NV) {
    int i = blockIdx.x * blockDim.x + threadIdx.x;
    if (i >= NV) return;

    float m0 = 0.f, m1 = 0.f, m2 = 0.f, m3 = 0.f;
    float s0 = 0.f, s1 = 0.f, s2 = 0.f, s3 = 0.f;

#pragma unroll
    for (int t = 0; t < T; ++t) {
        f32x4 xt = x[(size_t)t * NV + i];

        // keep = (1 - mask) is exactly 0.0 or 1.0; mem*0.25 is an exact
        // exponent shift -> single rounding at the add, matches numpy bitwise.
        m0 = m0 * 0.25f * ((s0 > 0.f) ? 0.f : 1.f) + xt.x;
        m1 = m1 * 0.25f * ((s1 > 0.f) ? 0.f : 1.f) + xt.y;
        m2 = m2 * 0.25f * ((s2 > 0.f) ? 0.f : 1.f) + xt.z;
        m3 = m3 * 0.25f * ((s3 > 0.f) ? 0.f : 1.f) + xt.w;

        s0 = msf_count(m0);
        s1 = msf_count(m1);
        s2 = msf_count(m2);
        s3 = msf_count(m3);

        f32x4 o;
        o.x = s0; o.y = s1; o.z = s2; o.w = s3;
        // nt store: don't let the output stream claim L2/L3 capacity.
        __builtin_nontemporal_store(o, &out[(size_t)t * NV + i]);
    }
}

extern "C" void kernel_launch(void* const* d_in, const int* in_sizes, int n_in,
                              void* d_out, int out_size, void* d_ws, size_t ws_size,
                              hipStream_t stream) {
    const float* x = (const float*)d_in[0];
    float* out = (float*)d_out;

    const int total = out_size;          // T * B * C * H * W = 33,554,432
    const int N = total / T;             // neurons per timestep = 4,194,304
    const int NV = N / 4;                // float4 groups = 1,048,576

    const int block = 256;
    const int grid = (NV + block - 1) / block;  // 4096

    mem_update_msf_kernel<<<grid, block, 0, stream>>>(
        (const f32x4*)x, (f32x4*)out, NV);
}

// Round 4
// 44.789 us; speedup vs baseline: 1.0062x; 1.0004x over previous
//
#include <hip/hip_runtime.h>

// mem_update_MSF: LIF-style membrane update with multi-synaptic fire.
// x: [T=8, B=32, C=128, H=32, W=32] f32.  out same shape, f32 spike counts.
// Recurrence per neuron i:
//   mask = spike>0; mem = mem*0.25*(1-mask) + x[t]; spike = sum_d (mem >= 0.5+d)
// Memory-bound streaming.
// R3: system-scope non-temporal stores (inline asm `sc0 sc1 nt`) — attempt to
//     keep the 134MB output stream from allocating in the 256MB Infinity Cache
//     so x becomes fully L3-resident across graph replays.
//     (R2 showed plain `nt` does NOT reduce FETCH_SIZE.)

constexpr int T = 8;

typedef float f32x4 __attribute__((ext_vector_type(4)));

__device__ __forceinline__ float msf_count(float m) {
    // Explicit threshold compares — exact match to the reference's Heaviside sum.
    float s = (m >= 0.5f) ? 1.0f : 0.0f;
    s += (m >= 1.5f) ? 1.0f : 0.0f;
    s += (m >= 2.5f) ? 1.0f : 0.0f;
    s += (m >= 3.5f) ? 1.0f : 0.0f;
    return s;
}

__device__ __forceinline__ void store_stream(f32x4 v, f32x4* p) {
    // System-scope + non-temporal: write through, no cache allocation.
    asm volatile("global_store_dwordx4 %0, %1, off sc0 sc1 nt"
                 :
                 : "v"(p), "v"(v)
                 : "memory");
}

__global__ __launch_bounds__(256) void mem_update_msf_kernel(
        const f32x4* __restrict__ x, f32x4* __restrict__ out, int NV) {
    int i = blockIdx.x * blockDim.x + threadIdx.x;
    if (i >= NV) return;

    float m0 = 0.f, m1 = 0.f, m2 = 0.f, m3 = 0.f;
    float s0 = 0.f, s1 = 0.f, s2 = 0.f, s3 = 0.f;

#pragma unroll
    for (int t = 0; t < T; ++t) {
        f32x4 xt = x[(size_t)t * NV + i];

        // keep = (1 - mask) is exactly 0.0 or 1.0; mem*0.25 is an exact
        // exponent shift -> single rounding at the add, matches numpy bitwise.
        m0 = m0 * 0.25f * ((s0 > 0.f) ? 0.f : 1.f) + xt.x;
        m1 = m1 * 0.25f * ((s1 > 0.f) ? 0.f : 1.f) + xt.y;
        m2 = m2 * 0.25f * ((s2 > 0.f) ? 0.f : 1.f) + xt.z;
        m3 = m3 * 0.25f * ((s3 > 0.f) ? 0.f : 1.f) + xt.w;

        s0 = msf_count(m0);
        s1 = msf_count(m1);
        s2 = msf_count(m2);
        s3 = msf_count(m3);

        f32x4 o;
        o.x = s0; o.y = s1; o.z = s2; o.w = s3;
        store_stream(o, &out[(size_t)t * NV + i]);
    }
}

extern "C" void kernel_launch(void* const* d_in, const int* in_sizes, int n_in,
                              void* d_out, int out_size, void* d_ws, size_t ws_size,
                              hipStream_t stream) {
    const float* x = (const float*)d_in[0];
    float* out = (float*)d_out;

    const int total = out_size;          // T * B * C * H * W = 33,554,432
    const int N = total / T;             // neurons per timestep = 4,194,304
    const int NV = N / 4;                // float4 groups = 1,048,576

    const int block = 256;
    const int grid = (NV + block - 1) / block;  // 4096

    mem_update_msf_kernel<<<grid, block, 0, stream>>>(
        (const f32x4*)x, (f32x4*)out, NV);
}